// Round 7
// baseline (487.304 us; speedup 1.0000x reference)
//
#include <hip/hip_runtime.h>
#include <math.h>

#define CIN 3
#define HIN 256
#define WIN 256
#define ND 256
#define NK 512
#define HP 128
#define WP 128
#define NPOS (HP*WP)
#define NB 16
#define QOUT ((size_t)NB*(size_t)ND*(size_t)NPOS)      // 67108864
#define IDXOUT ((size_t)NB*(size_t)NPOS)               // 262144
#define LOSS_OFF (QOUT + IDXOUT)
#define REFINE_EPS 0.09f
#define MAX_REFINE 16
#define BN_EPSF 1e-5f
#define SSHIFT 256.0f

// tile: 2 pooled rows x 32 pooled cols = 64 positions per block
#define HR 6
#define HC 66
#define HCH 70                 // padded stride for fp16 halo
#define HALO_N (CIN*HR*HC)     // 1188

typedef _Float16 f16x8 __attribute__((ext_vector_type(8)));
typedef float    f32x4 __attribute__((ext_vector_type(4)));

// ws byte layout: c2s f32[512] @0 ; vqh f16[256*512] @2048 (NEGATED codes);
// cwh f16[16*512] @264192 ; scale f32[256] @280576 ; shift f32[256] @281600
#define WS_VQH_B 2048
#define WS_CWH_B 264192
#define WS_SC_B  280576
#define WS_SH_B  281600

struct SMem {
    alignas(16) unsigned short xe[64 * ND];    // fp16 bits, swizzled, 32 KiB
    union {                                    // conv-phase vs post-screen
        _Float16 halo_h[CIN * HR * HCH];       // 2.46 KiB (conv A gather)
        struct { unsigned ms1[256], ms2[256], ms3[256]; } m;  // 3 KiB
    } u;
    int   bestidx[64];
    int   refine_pos[MAX_REFINE];
    int   refine_c[MAX_REFINE][3];
    int   refine_count;
    float sqbuf[4];
    float s1tot;
    double red[32];
};

// scores are guaranteed positive -> positive-float bits are order-isomorphic
__device__ __forceinline__ unsigned pack_pos(float s, int n) {
    return (__builtin_bit_cast(unsigned, s) & 0xFFFFFE00u) | (unsigned)n;
}
__device__ __forceinline__ float unpack_pos(unsigned u) {
    return __builtin_bit_cast(float, u & 0xFFFFFE00u);
}
// 4-op sorted-insert into ascending (b1,b2,b3)
__device__ __forceinline__ void insert3(unsigned v, unsigned& b1,
                                        unsigned& b2, unsigned& b3) {
    unsigned t = max(v, b2);           // candidate for 3rd place
    unsigned m;
    asm("v_med3_u32 %0, %1, %2, %3" : "=v"(m) : "v"(v), "v"(b1), "v"(b2));
    b1 = min(v, b1);
    b2 = m;
    b3 = min(b3, t);
}

// branchless exact-GELU: Abramowitz-Stegun 7.1.26 erf, |err| <= 1.5e-7
__device__ __forceinline__ float gelu_exact(float v) {
    float z = v * 0.7071067811865476f;
    float az = fabsf(z);
    float t = __builtin_amdgcn_rcpf(fmaf(0.3275911f, az, 1.0f));
    float p = fmaf(1.061405429f, t, -1.453152027f);
    p = fmaf(p, t, 1.421413741f);
    p = fmaf(p, t, -0.284496736f);
    p = fmaf(p, t, 0.254829592f);
    p = p * t;
    float e = __expf(-az * az);
    float erf_az = fmaf(-p, e, 1.0f);          // 1 - erfc
    float er = copysignf(erf_az, z);
    return 0.5f * v * (1.0f + er);
}

__global__ void prep_kernel(const float* __restrict__ cb,
                            const float* __restrict__ conv_w,
                            const float* __restrict__ conv_b,
                            const float* __restrict__ gamma,
                            const float* __restrict__ beta,
                            const float* __restrict__ mean,
                            const float* __restrict__ var,
                            float* __restrict__ c2s,
                            _Float16* __restrict__ vqh,
                            _Float16* __restrict__ cwh,
                            float* __restrict__ scale,
                            float* __restrict__ shift,
                            float* __restrict__ loss_out) {
    const int blk = blockIdx.x;
    const int t = threadIdx.x;
    if (blk < 64) {
        // NEGATED VQ code fragments (fp16), MFMA A-operand, rows=codes:
        // frag fr = nt*8 + s; lane l: code n = nt*16+(l&15), d = s*32+(l>>4)*8+e
        const int fr = blk * 4 + (t >> 6);
        const int lane = t & 63;
        const int nt = fr >> 3, s = fr & 7;
        const int n = nt * 16 + (lane & 15);
        const int dbase = s * 32 + ((lane >> 4) << 3);
        const float* src = cb + (size_t)n * ND + dbase;
        f16x8 vh;
        #pragma unroll
        for (int e = 0; e < 8; e++) vh[e] = (_Float16)(-src[e]);
        *reinterpret_cast<f16x8*>(&vqh[(size_t)fr * 512 + lane * 8]) = vh;
    } else if (blk == 64) {
        for (int c = t; c < NK; c += 256) {
            const float4* row = reinterpret_cast<const float4*>(cb + (size_t)c * ND);
            float s = 0.f;
            #pragma unroll 8
            for (int i = 0; i < ND / 4; i++) {
                float4 v = row[i];
                s = fmaf(v.x, v.x, s); s = fmaf(v.y, v.y, s);
                s = fmaf(v.z, v.z, s); s = fmaf(v.w, v.w, s);
            }
            c2s[c] = 0.5f * s + SSHIFT;
        }
        {
            int ch = t;
            float inv = gamma[ch] / sqrtf(var[ch] + BN_EPSF);
            scale[ch] = inv;
            shift[ch] = (conv_b[ch] - mean[ch]) * inv + beta[ch];
        }
        if (t == 0) *loss_out = 0.f;
    } else {
        // conv-weight fragments (fp16): 16 N-tiles, K=32 (27 real + 5 zero)
        const int lane = t & 63;
        for (int fr = t >> 6; fr < 16; fr += 4) {
            const int n = fr * 16 + (lane & 15);
            f16x8 vh;
            #pragma unroll
            for (int e = 0; e < 8; e++) {
                int k = ((lane >> 4) << 3) + e;
                vh[e] = (k < 27) ? (_Float16)conv_w[n * 27 + k] : (_Float16)0.f;
            }
            *reinterpret_cast<f16x8*>(&cwh[(size_t)fr * 512 + lane * 8]) = vh;
        }
    }
}

__global__ __launch_bounds__(256, 4)
void vqvae_kernel(const float* __restrict__ x, const float* __restrict__ conv_w,
                  const float* __restrict__ cb, const float* __restrict__ c2s,
                  const float* __restrict__ conv_bp,
                  const float* __restrict__ gamma, const float* __restrict__ beta,
                  const float* __restrict__ mean, const float* __restrict__ var,
                  const _Float16* __restrict__ vqh,
                  const _Float16* __restrict__ cwh,
                  const float* __restrict__ scale,
                  const float* __restrict__ shift,
                  float* __restrict__ out) {
    __shared__ SMem sm;
    const int t = threadIdx.x;
    const int l = t & 63;
    const int wv = t >> 6;
    const int blk = blockIdx.x;
    const int b = blk >> 8;
    const int tile = blk & 255;
    const int ty0 = (tile >> 2) * 2;        // pooled-row origin
    const int tx0 = (tile & 3) * 32;        // pooled-col origin

    // -------------- stage input halo as fp16 (zero-padded) ------------------
    {
        const int iy0 = ty0 * 2 - 1;
        const int ix0 = tx0 * 2 - 1;
        for (int e = t; e < HALO_N; e += 256) {
            int c = e / (HR * HC);
            int rem = e - c * (HR * HC);
            int r = rem / HC;
            int cc = rem - r * HC;
            int iy = iy0 + r, ix = ix0 + cc;
            float v = 0.f;
            if (iy >= 0 && iy < HIN && ix >= 0 && ix < WIN)
                v = x[(((size_t)b * CIN + c) * HIN + iy) * WIN + ix];
            sm.u.halo_h[c * (HR * HCH) + r * HCH + cc] = (_Float16)v;
        }
        if (t == 0) sm.refine_count = 0;
    }

    // per-lane k -> fp16-halo offset (k = (l>>4)*8 + e)
    int hoff2[8];
    #pragma unroll
    for (int e = 0; e < 8; e++) {
        int k = ((l >> 4) << 3) + e;
        int c = k / 9;
        int r9 = k - c * 9;
        int dy = r9 / 3;
        int dx = r9 - dy * 3;
        hoff2[e] = (k < 27) ? (c * (HR * HCH) + dy * HCH + dx) : 0;
    }

    // folded BN params for this wave's 64 channels (4 N-tiles)
    float sc4[4], sh4[4];
    #pragma unroll
    for (int j = 0; j < 4; j++) {
        int ch = wv * 64 + j * 16 + (l & 15);
        sc4[j] = scale[ch];
        sh4[j] = shift[ch];
    }
    __syncthreads();

    // ------- conv3x3 via im2col fp16 MFMA + maxpool + BN + exact GELU -------
    float sq = 0.f;
    #pragma unroll 1
    for (int mc = 0; mc < 4; mc++) {
        f16x8 ah[4];
        #pragma unroll
        for (int i = 0; i < 4; i++) {
            const int m16 = l & 15;
            const int p = i * 4 + (m16 >> 2);
            const int q = m16 & 3;
            const int pos = mc * 16 + p;
            const int py = pos >> 5, px = pos & 31;
            const int cy = py * 2 + (q >> 1), cx = px * 2 + (q & 1);
            const int base = cy * HCH + cx;
            #pragma unroll
            for (int e = 0; e < 8; e++)
                ah[i][e] = sm.u.halo_h[base + hoff2[e]];  // k>=27: junk x 0-w
        }
        #pragma unroll 1
        for (int jh = 0; jh < 2; jh++) {
            f16x8 bw0 = *reinterpret_cast<const f16x8*>(
                &cwh[(wv * 4 + jh * 2 + 0) * 512 + l * 8]);
            f16x8 bw1 = *reinterpret_cast<const f16x8*>(
                &cwh[(wv * 4 + jh * 2 + 1) * 512 + l * 8]);
            f32x4 acc[4][2];
            #pragma unroll
            for (int i = 0; i < 4; i++) {
                acc[i][0] = (f32x4){0.f, 0.f, 0.f, 0.f};
                acc[i][1] = (f32x4){0.f, 0.f, 0.f, 0.f};
            }
            #pragma unroll
            for (int i = 0; i < 4; i++) {
                acc[i][0] = __builtin_amdgcn_mfma_f32_16x16x32_f16(ah[i], bw0, acc[i][0], 0, 0, 0);
                acc[i][1] = __builtin_amdgcn_mfma_f32_16x16x32_f16(ah[i], bw1, acc[i][1], 0, 0, 0);
            }
            #pragma unroll
            for (int i = 0; i < 4; i++) {
                const int pos = mc * 16 + i * 4 + (l >> 4);
                #pragma unroll
                for (int jj = 0; jj < 2; jj++) {
                    const int j = jh * 2 + jj;
                    f32x4 a4 = acc[i][jj];
                    float m = fmaxf(fmaxf(a4[0], a4[1]), fmaxf(a4[2], a4[3]));
                    float bn = fmaf(m, sc4[j], sh4[j]);
                    float g = gelu_exact(bn);
                    sq = fmaf(g, g, sq);
                    _Float16 h = (_Float16)g;
                    int ch = wv * 64 + j * 16 + (l & 15);
                    int slot = pos * ND + (((ch >> 3) ^ (pos & 7)) << 3) + (ch & 7);
                    sm.xe[slot] = __builtin_bit_cast(unsigned short, h);
                }
            }
        }
    }
    #pragma unroll
    for (int off = 32; off; off >>= 1) sq += __shfl_xor(sq, off, 64);
    if (l == 0) sm.sqbuf[wv] = sq;
    __syncthreads();   // all halo_h reads done; u switches to ms after screen

    // ----- VQ screening: operand-swapped fp16 MFMA (A=-codes, B=x tile) -----
    // C initialized with 0.5|c|^2+SSHIFT so acc == score after the K loop.
    unsigned pb1[4], pb2[4], pb3[4];
    #pragma unroll
    for (int j = 0; j < 4; j++) {
        pb1[j] = 0xFFFFFFFFu; pb2[j] = 0xFFFFFFFFu; pb3[j] = 0xFFFFFFFFu;
    }

    #pragma unroll 1
    for (int cg = 0; cg < 4; ++cg) {          // pairs of code tiles
        f32x4 acc[2][4];
        #pragma unroll
        for (int tt = 0; tt < 2; tt++) {
            int cbase = (wv * 8 + cg * 2 + tt) * 16 + ((l >> 4) << 2);
            float4 c2q = *reinterpret_cast<const float4*>(&c2s[cbase]);
            f32x4 ci = {c2q.x, c2q.y, c2q.z, c2q.w};
            #pragma unroll
            for (int j = 0; j < 4; j++) acc[tt][j] = ci;
        }

        #pragma unroll 2
        for (int s = 0; s < 8; ++s) {
            f16x8 bx[4];
            #pragma unroll
            for (int j = 0; j < 4; ++j) {
                int n = j * 16 + (l & 15);        // position
                int g = s * 4 + (l >> 4);
                int gp = g ^ (n & 7);
                bx[j] = *reinterpret_cast<const f16x8*>(&sm.xe[n * ND + gp * 8]);
            }
            #pragma unroll
            for (int tt = 0; tt < 2; ++tt) {
                int ct = wv * 8 + cg * 2 + tt;
                f16x8 ac = *reinterpret_cast<const f16x8*>(
                    &vqh[(size_t)(ct * 8 + s) * 512 + l * 8]);
                #pragma unroll
                for (int j = 0; j < 4; ++j)
                    acc[tt][j] = __builtin_amdgcn_mfma_f32_16x16x32_f16(ac, bx[j], acc[tt][j], 0, 0, 0);
            }
        }
        #pragma unroll
        for (int tt = 0; tt < 2; ++tt) {
            int cbase = (wv * 8 + cg * 2 + tt) * 16 + ((l >> 4) << 2);
            #pragma unroll
            for (int j = 0; j < 4; ++j) {
                insert3(pack_pos(acc[tt][j][0], cbase + 0), pb1[j], pb2[j], pb3[j]);
                insert3(pack_pos(acc[tt][j][1], cbase + 1), pb1[j], pb2[j], pb3[j]);
                insert3(pack_pos(acc[tt][j][2], cbase + 2), pb1[j], pb2[j], pb3[j]);
                insert3(pack_pos(acc[tt][j][3], cbase + 3), pb1[j], pb2[j], pb3[j]);
            }
        }
    }

    // merge across the 4 lanes sharing a position column (xor 16, 32)
    #pragma unroll
    for (int j = 0; j < 4; ++j) {
        unsigned a1 = pb1[j], a2 = pb2[j], a3 = pb3[j];
        #pragma unroll
        for (int off = 16; off <= 32; off <<= 1) {
            unsigned o1 = __shfl_xor((int)a1, off, 64);
            unsigned o2 = __shfl_xor((int)a2, off, 64);
            unsigned o3 = __shfl_xor((int)a3, off, 64);
            insert3(o1, a1, a2, a3);
            insert3(o2, a1, a2, a3);
            insert3(o3, a1, a2, a3);
        }
        if (l < 16) {
            sm.u.m.ms1[wv * 64 + j * 16 + l] = a1;
            sm.u.m.ms2[wv * 64 + j * 16 + l] = a2;
            sm.u.m.ms3[wv * 64 + j * 16 + l] = a3;
        }
    }
    __syncthreads();

    // cross-wave merge (waves cover disjoint code ranges)
    if (t < 64) {
        unsigned b1 = 0xFFFFFFFFu, b2 = 0xFFFFFFFFu, b3 = 0xFFFFFFFFu;
        #pragma unroll
        for (int w = 0; w < 4; ++w) {
            insert3(sm.u.m.ms1[w * 64 + t], b1, b2, b3);
            insert3(sm.u.m.ms2[w * 64 + t], b1, b2, b3);
            insert3(sm.u.m.ms3[w * 64 + t], b1, b2, b3);
        }
        sm.bestidx[t] = (int)(b1 & 511u);
        float s1f = unpack_pos(b1), s2f = unpack_pos(b2);
        if (s2f - s1f < REFINE_EPS) {
            int slot = atomicAdd(&sm.refine_count, 1);
            if (slot < MAX_REFINE) {
                sm.refine_pos[slot] = t;
                sm.refine_c[slot][0] = (int)(b1 & 511u);
                sm.refine_c[slot][1] = (int)(b2 & 511u);
                sm.refine_c[slot][2] = (int)(b3 & 511u);
            }
        }
        float s1 = s1f;
        #pragma unroll
        for (int off = 32; off; off >>= 1) s1 += __shfl_xor(s1, off, 64);
        if (t == 0) sm.s1tot = s1;
    }
    __syncthreads();

    // ---- rare double-precision refinement (3 candidates, x from global) ----
    {
        int nref = sm.refine_count;
        if (nref > MAX_REFINE) nref = MAX_REFINE;
        const float* xb = x + (size_t)b * CIN * HIN * WIN;
        for (int rr = 0; rr < nref; rr++) {
            const int pos = sm.refine_pos[rr];
            const int d = t;
            const int py = pos >> 5, px = pos & 31;
            const int iy0 = (ty0 + py) * 2 - 1;     // conv window rows iy0..+3
            const int ix0 = (tx0 + px) * 2 - 1;     // cols ix0..+3
            double s00, s01, s10, s11;
            s00 = s01 = s10 = s11 = (double)conv_bp[d];
            for (int c = 0; c < 3; c++) {
                const float* xc = xb + (size_t)c * HIN * WIN;
                for (int r = 0; r < 4; r++) {
                    const int iy = iy0 + r;
                    const bool rowok = (iy >= 0) && (iy < HIN);
                    const float* xr = xc + (size_t)(rowok ? iy : 0) * WIN;
                    double v0 = 0.0, v1 = 0.0, v2 = 0.0, v3 = 0.0;
                    if (rowok) {
                        int i0 = ix0;
                        v0 = (i0 >= 0     && i0 < WIN)     ? (double)xr[i0]     : 0.0;
                        v1 = (i0 + 1 >= 0 && i0 + 1 < WIN) ? (double)xr[i0 + 1] : 0.0;
                        v2 = (i0 + 2 >= 0 && i0 + 2 < WIN) ? (double)xr[i0 + 2] : 0.0;
                        v3 = (i0 + 3 < WIN)                ? (double)xr[i0 + 3] : 0.0;
                    }
                    if (r <= 2) {
                        double w0 = (double)conv_w[d*27 + c*9 + r*3 + 0];
                        double w1 = (double)conv_w[d*27 + c*9 + r*3 + 1];
                        double w2 = (double)conv_w[d*27 + c*9 + r*3 + 2];
                        s00 = fma(w0, v0, s00); s00 = fma(w1, v1, s00); s00 = fma(w2, v2, s00);
                        s01 = fma(w0, v1, s01); s01 = fma(w1, v2, s01); s01 = fma(w2, v3, s01);
                    }
                    if (r >= 1) {
                        double w0 = (double)conv_w[d*27 + c*9 + (r-1)*3 + 0];
                        double w1 = (double)conv_w[d*27 + c*9 + (r-1)*3 + 1];
                        double w2 = (double)conv_w[d*27 + c*9 + (r-1)*3 + 2];
                        s10 = fma(w0, v0, s10); s10 = fma(w1, v1, s10); s10 = fma(w2, v2, s10);
                        s11 = fma(w0, v1, s11); s11 = fma(w1, v2, s11); s11 = fma(w2, v3, s11);
                    }
                }
            }
            double m = fmax(fmax(s00, s01), fmax(s10, s11));
            double bn = (m - (double)mean[d]) * ((double)gamma[d] /
                        sqrt((double)var[d] + 1e-5)) + (double)beta[d];
            double xd = 0.5 * bn * (1.0 + erf(bn * 0.70710678118654752440));
            double p[3], q[3];
            #pragma unroll
            for (int k = 0; k < 3; k++) {
                double cv = (double)cb[(size_t)sm.refine_c[rr][k] * ND + d];
                p[k] = xd * cv;
                q[k] = cv * cv;
            }
            #pragma unroll
            for (int k = 0; k < 3; k++) {
                for (int off = 32; off; off >>= 1) {
                    p[k] += __shfl_xor(p[k], off, 64);
                    q[k] += __shfl_xor(q[k], off, 64);
                }
            }
            if ((t & 63) == 0) {
                #pragma unroll
                for (int k = 0; k < 3; k++) {
                    sm.red[wv * 8 + k * 2 + 0] = p[k];
                    sm.red[wv * 8 + k * 2 + 1] = q[k];
                }
            }
            __syncthreads();
            if (t == 0) {
                double bsc = 1e300; int bidx = 0x7fffffff;
                #pragma unroll
                for (int k = 0; k < 3; k++) {
                    double dot = sm.red[k*2] + sm.red[8 + k*2] + sm.red[16 + k*2] + sm.red[24 + k*2];
                    double cs  = sm.red[k*2+1] + sm.red[8 + k*2+1] + sm.red[16 + k*2+1] + sm.red[24 + k*2+1];
                    double sc = 0.5 * cs - dot;
                    int ci = sm.refine_c[rr][k];
                    if (sc < bsc || (sc == bsc && ci < bidx)) { bsc = sc; bidx = ci; }
                }
                sm.bestidx[pos] = bidx;
            }
            __syncthreads();
        }
    }
    __syncthreads();

    // --------------- write indices, quant (NCHW, 128B runs), loss -----------
    if (t < 64) {
        const int hw = (ty0 + (t >> 5)) * WP + tx0 + (t & 31);
        out[QOUT + (size_t)b * NPOS + hw] = (float)sm.bestidx[t];
    }
    {
        const int code = sm.bestidx[l];
        const int hw = (ty0 + (l >> 5)) * WP + tx0 + (l & 31);
        const float* crow = cb + (size_t)code * ND + wv * 64;
        float* qb = out + (size_t)b * ND * NPOS + hw;
        #pragma unroll
        for (int k4 = 0; k4 < 16; ++k4) {
            float4 cv = *reinterpret_cast<const float4*>(&crow[k4 * 4]);
            const size_t d0 = (size_t)(wv * 64 + k4 * 4);
            qb[(d0 + 0) * NPOS] = cv.x;
            qb[(d0 + 1) * NPOS] = cv.y;
            qb[(d0 + 2) * NPOS] = cv.z;
            qb[(d0 + 3) * NPOS] = cv.w;
        }
    }
    if (t == 0) {
        // per-position dist = |x|^2 + 2*(s1 - SSHIFT); 64 positions per block
        float tot = sm.sqbuf[0] + sm.sqbuf[1] + sm.sqbuf[2] + sm.sqbuf[3]
                  + 2.0f * (sm.s1tot - 64.0f * SSHIFT);
        atomicAdd(out + LOSS_OFF, tot * (1.0f / 67108864.0f));
    }
}

extern "C" void kernel_launch(void* const* d_in, const int* in_sizes, int n_in,
                              void* d_out, int out_size, void* d_ws, size_t ws_size,
                              hipStream_t stream) {
    const float* x      = (const float*)d_in[0];
    const float* conv_w = (const float*)d_in[1];
    const float* conv_b = (const float*)d_in[2];
    const float* gammap = (const float*)d_in[3];
    const float* betap  = (const float*)d_in[4];
    const float* meanp  = (const float*)d_in[5];
    const float* varp   = (const float*)d_in[6];
    const float* cb     = (const float*)d_in[7];
    float* out = (float*)d_out;

    char* wsb = (char*)d_ws;
    float*    c2w  = (float*)wsb;
    _Float16* vqh  = (_Float16*)(wsb + WS_VQH_B);
    _Float16* cwh  = (_Float16*)(wsb + WS_CWH_B);
    float*    scp  = (float*)(wsb + WS_SC_B);
    float*    shp  = (float*)(wsb + WS_SH_B);

    prep_kernel<<<66, 256, 0, stream>>>(cb, conv_w, conv_b, gammap, betap,
                                        meanp, varp, c2w, vqh, cwh, scp, shp,
                                        out + LOSS_OFF);
    vqvae_kernel<<<NB * 256, 256, 0, stream>>>(x, conv_w, cb, c2w, conv_b,
                                               gammap, betap, meanp, varp,
                                               vqh, cwh, scp, shp, out);
}